// Round 1
// baseline (544.010 us; speedup 1.0000x reference)
//
#include <hip/hip_runtime.h>
#include <math.h>

// SubGraphTransformer: B=8,N=512,E=256,H=8,HD=32,FF=1024,TOPK=102.
// KEY INSIGHT: Floyd-Warshall is dead code. Mask = -inf where binary==0; on
// surviving (binary==1) entries dist==1 (direct edge) except diagonal (dist==0).
// Row-constant bias emb[2][h] cancels under softmax; only the diagonal delta
// emb[1][h]-emb[2][h] survives. So we need only the top-k bitmask + delta_h.

#define B_ 8
#define N_ 512
#define E_ 256
#define H_ 8
#define HD_ 32
#define TOPK_ 102

// ---------------- 1. top-k(102) per row -> 512-bit mask ----------------
__global__ __launch_bounds__(256) void topk_kernel(const float* __restrict__ adj,
                                                   unsigned int* __restrict__ bits) {
  const int row = blockIdx.x;  // b*N + i
  const float* a = adj + (size_t)row * N_;
  __shared__ float vals[N_];
  __shared__ unsigned int hist[1024];
  __shared__ int scan[256];
  __shared__ int s_bb;
  __shared__ int s_higher;
  __shared__ unsigned int rowbits[16];
  const int t = threadIdx.x;

  hist[t] = 0u; hist[t + 256] = 0u; hist[t + 512] = 0u; hist[t + 768] = 0u;
  if (t < 16) rowbits[t] = 0u;
  float v0 = a[t];
  float v1 = a[t + 256];
  vals[t] = v0; vals[t + 256] = v1;
  __syncthreads();
  // values uniform [0,1): v*1024 is exact (pow2 scale); floor via int cast
  int b0 = min(1023, max(0, (int)(v0 * 1024.0f)));
  int b1 = min(1023, max(0, (int)(v1 * 1024.0f)));
  atomicAdd(&hist[b0], 1u);
  atomicAdd(&hist[b1], 1u);
  __syncthreads();
  // thread t owns 4 buckets counting down from the top
  const int base = 1020 - 4 * t;
  int g = (int)(hist[base] + hist[base + 1] + hist[base + 2] + hist[base + 3]);
  scan[t] = g;
  __syncthreads();
  for (int off = 1; off < 256; off <<= 1) {  // Hillis-Steele inclusive scan
    int y = (t >= off) ? scan[t - off] : 0;
    __syncthreads();
    scan[t] += y;
    __syncthreads();
  }
  int incl = scan[t];
  int excl = incl - g;
  if (excl < TOPK_ && incl >= TOPK_) {  // exactly one thread
    int cum = excl;
    int bb = base;
    for (int u = 3; u >= 0; u--) {  // top-down inside group
      int hh = (int)hist[base + u];
      if (cum + hh >= TOPK_) { bb = base + u; break; }
      cum += hh;
    }
    s_bb = bb;
    s_higher = cum;
  }
  __syncthreads();
  const int bb = s_bb;
  const int need = TOPK_ - s_higher;
  #pragma unroll
  for (int rep = 0; rep < 2; rep++) {
    int idx = t + rep * 256;
    float v = (rep == 0) ? v0 : v1;
    int bk = min(1023, max(0, (int)(v * 1024.0f)));
    bool sel = false;
    if (bk > bb) {
      sel = true;
    } else if (bk == bb) {
      // exact jax.lax.top_k order: (value desc, index asc)
      int r = 0;
      for (int j = 0; j < N_; j++) {
        float vj = vals[j];
        int bj = min(1023, max(0, (int)(vj * 1024.0f)));
        if (bj == bb && (vj > v || (vj == v && j < idx))) r++;
      }
      sel = (r < need);
    }
    if (sel) atomicOr(&rowbits[idx >> 5], 1u << (idx & 31));
  }
  __syncthreads();
  if (t < 16) bits[(size_t)row * 16 + t] = rowbits[t];
}

// ---------------- 2. fp32 GEMM: C[M,N] = A[M,K] * B[N,K]^T + bias (+res)(relu)
__global__ __launch_bounds__(256) void gemm_bt_kernel(
    const float* __restrict__ A, const float* __restrict__ Bw,
    const float* __restrict__ bias, const float* __restrict__ res,
    float* __restrict__ C, int M, int N, int K, int relu) {
  __shared__ float As[16][68];
  __shared__ float Bs[16][68];
  const int tid = threadIdx.x;
  const int tx = tid & 15;
  const int ty = tid >> 4;
  const int m0 = blockIdx.y * 64;
  const int n0 = blockIdx.x * 64;
  const int lrow = tid >> 2;        // 0..63
  const int lk4 = (tid & 3) * 4;    // 0,4,8,12
  const float* Ap = A + (size_t)(m0 + lrow) * K + lk4;
  const float* Bp = Bw + (size_t)(n0 + lrow) * K + lk4;
  float acc[4][4] = {{0.f, 0.f, 0.f, 0.f}, {0.f, 0.f, 0.f, 0.f},
                     {0.f, 0.f, 0.f, 0.f}, {0.f, 0.f, 0.f, 0.f}};
  for (int k0 = 0; k0 < K; k0 += 16) {
    float4 av = *(const float4*)(Ap + k0);
    float4 bv = *(const float4*)(Bp + k0);
    __syncthreads();
    As[lk4 + 0][lrow] = av.x;
    As[lk4 + 1][lrow] = av.y;
    As[lk4 + 2][lrow] = av.z;
    As[lk4 + 3][lrow] = av.w;
    Bs[lk4 + 0][lrow] = bv.x;
    Bs[lk4 + 1][lrow] = bv.y;
    Bs[lk4 + 2][lrow] = bv.z;
    Bs[lk4 + 3][lrow] = bv.w;
    __syncthreads();
    #pragma unroll
    for (int kk = 0; kk < 16; kk++) {
      float4 a4 = *(const float4*)&As[kk][ty * 4];
      float4 b4 = *(const float4*)&Bs[kk][tx * 4];
      float aa[4] = {a4.x, a4.y, a4.z, a4.w};
      float bb[4] = {b4.x, b4.y, b4.z, b4.w};
      #pragma unroll
      for (int i = 0; i < 4; i++)
        #pragma unroll
        for (int j = 0; j < 4; j++) acc[i][j] += aa[i] * bb[j];
    }
  }
  float4 bsv = *(const float4*)(bias + n0 + tx * 4);
  float bvv[4] = {bsv.x, bsv.y, bsv.z, bsv.w};
  #pragma unroll
  for (int i = 0; i < 4; i++) {
    int m = m0 + ty * 4 + i;
    float o[4];
    #pragma unroll
    for (int j = 0; j < 4; j++) o[j] = acc[i][j] + bvv[j];
    if (res) {
      float4 rv = *(const float4*)(res + (size_t)m * N + n0 + tx * 4);
      o[0] += rv.x; o[1] += rv.y; o[2] += rv.z; o[3] += rv.w;
    }
    if (relu) {
      #pragma unroll
      for (int j = 0; j < 4; j++) o[j] = fmaxf(o[j], 0.f);
    }
    float4 ov = make_float4(o[0], o[1], o[2], o[3]);
    *(float4*)(C + (size_t)m * N + n0 + tx * 4) = ov;
  }
}

// ---------------- 3. masked flash attention ----------------
// grid: b(8) x h(8) x i-block(8 of 64 rows); block 256 thr = 4 waves x 16 rows
__global__ __launch_bounds__(256, 2) void flash_attn_kernel(
    const float* __restrict__ qkv, const unsigned int* __restrict__ bits,
    const float* __restrict__ emb, float* __restrict__ ctxo) {
  const int bx = blockIdx.x;
  const int ib = bx & 7;
  const int h = (bx >> 3) & 7;
  const int b = bx >> 6;
  const int tid = threadIdx.x;
  const int lane = tid & 63;
  const int wave = __builtin_amdgcn_readfirstlane(tid >> 6);
  const int rr = lane >> 3;  // phase-C row pair 0..7
  const int dd = lane & 7;   // phase-C d-lane 0..7 (owns d = dd+8u)

  __shared__ float kT[32][68];      // kT[d][j]
  __shared__ float vT[32][68];      // vT[d][j]
  __shared__ float pS[4][16][68];   // per-wave P[r][j]

  const float delta = emb[1 * H_ + h] - emb[2 * H_ + h];
  const float scale = 0.17677669529663687f;  // 1/sqrt(32)

  float m_run[16], l_part[16];
  float cacc[2][4];
  #pragma unroll
  for (int r = 0; r < 16; r++) { m_run[r] = -1e30f; l_part[r] = 0.f; }
  #pragma unroll
  for (int e = 0; e < 2; e++)
    #pragma unroll
    for (int u = 0; u < 4; u++) cacc[e][u] = 0.f;

  const int sj = tid >> 2;  // staging row 0..63
  const int sc = tid & 3;   // staging chunk 0..3

  #pragma unroll 1
  for (int jt = 0; jt < 8; jt++) {
    __syncthreads();
    {  // stage k,v tiles transposed into LDS (coalesced global float4 reads)
      const float* krow = qkv + ((size_t)(b * N_ + jt * 64 + sj)) * 768 + E_ + h * HD_;
      float4 ka = *(const float4*)(krow + sc * 4);
      float4 kb = *(const float4*)(krow + sc * 4 + 16);
      const float* vrow = krow + E_;
      float4 va = *(const float4*)(vrow + sc * 4);
      float4 vb = *(const float4*)(vrow + sc * 4 + 16);
      kT[sc * 4 + 0][sj] = ka.x; kT[sc * 4 + 1][sj] = ka.y;
      kT[sc * 4 + 2][sj] = ka.z; kT[sc * 4 + 3][sj] = ka.w;
      kT[16 + sc * 4 + 0][sj] = kb.x; kT[16 + sc * 4 + 1][sj] = kb.y;
      kT[16 + sc * 4 + 2][sj] = kb.z; kT[16 + sc * 4 + 3][sj] = kb.w;
      vT[sc * 4 + 0][sj] = va.x; vT[sc * 4 + 1][sj] = va.y;
      vT[sc * 4 + 2][sj] = va.z; vT[sc * 4 + 3][sj] = va.w;
      vT[16 + sc * 4 + 0][sj] = vb.x; vT[16 + sc * 4 + 1][sj] = vb.y;
      vT[16 + sc * 4 + 2][sj] = vb.z; vT[16 + sc * 4 + 3][sj] = vb.w;
    }
    __syncthreads();
    // lane caches its k column (j = jt*64+lane) in VGPRs; bank = (4d+lane)%32 ok
    float kreg[32];
    #pragma unroll
    for (int d = 0; d < 32; d++) kreg[d] = kT[d][lane];

    float a0 = 1.f, a1 = 1.f;
    #pragma unroll
    for (int r = 0; r < 16; r++) {
      const int ig = ib * 64 + wave * 16 + r;
      const float* qrow = qkv + ((size_t)(b * N_ + ig)) * 768 + h * HD_;  // uniform -> s_load
      float s = 0.f;
      #pragma unroll
      for (int d4 = 0; d4 < 8; d4++) {
        float4 q4 = *(const float4*)(qrow + d4 * 4);
        s += q4.x * kreg[d4 * 4 + 0] + q4.y * kreg[d4 * 4 + 1] +
             q4.z * kreg[d4 * 4 + 2] + q4.w * kreg[d4 * 4 + 3];
      }
      s *= scale;
      unsigned int wb = bits[((size_t)(b * N_ + ig)) * 16 + jt * 2 + (lane >> 5)];
      bool allowed = ((wb >> (lane & 31)) & 1u) != 0u;
      int jg = jt * 64 + lane;
      s = allowed ? (s + ((jg == ig) ? delta : 0.f)) : -INFINITY;
      // online softmax (row max across 64 j-lanes)
      float mt = s;
      #pragma unroll
      for (int off = 1; off < 64; off <<= 1) mt = fmaxf(mt, __shfl_xor(mt, off));
      float mnew = fmaxf(m_run[r], mt);
      float al = __expf(m_run[r] - mnew);
      m_run[r] = mnew;
      float p = __expf(s - mnew);
      l_part[r] = l_part[r] * al + p;
      pS[wave][r][lane] = p;
      a0 = (r == 2 * rr) ? al : a0;
      a1 = (r == 2 * rr + 1) ? al : a1;
    }
    // phase C: ctx[r][d] += sum_j P[r][j] * v[j][d]
    #pragma unroll
    for (int u = 0; u < 4; u++) { cacc[0][u] *= a0; cacc[1][u] *= a1; }
    #pragma unroll
    for (int jq = 0; jq < 16; jq++) {
      float4 p0 = *(const float4*)&pS[wave][2 * rr][jq * 4];
      float4 p1 = *(const float4*)&pS[wave][2 * rr + 1][jq * 4];
      #pragma unroll
      for (int u = 0; u < 4; u++) {
        float4 v4 = *(const float4*)&vT[dd + 8 * u][jq * 4];  // banks 4dd+4jq: conflict-free
        cacc[0][u] += p0.x * v4.x + p0.y * v4.y + p0.z * v4.z + p0.w * v4.w;
        cacc[1][u] += p1.x * v4.x + p1.y * v4.y + p1.z * v4.z + p1.w * v4.w;
      }
    }
  }
  // finalize: row sums l, normalize, store ctx[b][i][h*32+d]
  float linv0 = 1.f, linv1 = 1.f;
  #pragma unroll
  for (int r = 0; r < 16; r++) {
    float lv = l_part[r];
    #pragma unroll
    for (int off = 1; off < 64; off <<= 1) lv += __shfl_xor(lv, off);
    if (r == 2 * rr) linv0 = 1.f / lv;
    if (r == 2 * rr + 1) linv1 = 1.f / lv;
  }
  const int i0 = ib * 64 + wave * 16 + 2 * rr;
  float* c0 = ctxo + ((size_t)(b * N_ + i0)) * E_ + h * HD_ + dd;
  #pragma unroll
  for (int u = 0; u < 4; u++) {
    c0[8 * u] = cacc[0][u] * linv0;
    c0[E_ + 8 * u] = cacc[1][u] * linv1;
  }
}

// ---------------- 4. LayerNorm over E=256 ----------------
__global__ __launch_bounds__(256) void layernorm_kernel(
    const float* __restrict__ t, const float* __restrict__ g,
    const float* __restrict__ be, float* __restrict__ out) {
  const int row = blockIdx.x;
  const int tid = threadIdx.x;
  float v = t[(size_t)row * E_ + tid];
  float s = v, s2 = v * v;
  #pragma unroll
  for (int off = 32; off > 0; off >>= 1) {
    s += __shfl_xor(s, off);
    s2 += __shfl_xor(s2, off);
  }
  __shared__ float sh[8];
  const int wave = tid >> 6, lane = tid & 63;
  if (lane == 0) { sh[wave] = s; sh[4 + wave] = s2; }
  __syncthreads();
  s = sh[0] + sh[1] + sh[2] + sh[3];
  s2 = sh[4] + sh[5] + sh[6] + sh[7];
  float mean = s * (1.f / 256.f);
  float var = s2 * (1.f / 256.f) - mean * mean;
  float inv = rsqrtf(var + 1e-5f);
  out[(size_t)row * E_ + tid] = (v - mean) * inv * g[tid] + be[tid];
}

// ---------------- 5. attention pooling ----------------
__global__ __launch_bounds__(256) void pool_kernel(
    const float* __restrict__ x2, const float* __restrict__ wp,
    const float* __restrict__ bp, float* __restrict__ out) {
  const int b = blockIdx.x;
  const int tid = threadIdx.x;
  const int wave = tid >> 6, lane = tid & 63;
  __shared__ float wgt[N_];
  __shared__ float red[8];
  const float* xb = x2 + (size_t)b * N_ * E_;
  float4 wv = *(const float4*)(wp + lane * 4);
  for (int n = wave; n < N_; n += 4) {
    float4 xv = *(const float4*)(xb + (size_t)n * E_ + lane * 4);
    float d = xv.x * wv.x + xv.y * wv.y + xv.z * wv.z + xv.w * wv.w;
    #pragma unroll
    for (int off = 32; off > 0; off >>= 1) d += __shfl_xor(d, off);
    if (lane == 0) wgt[n] = tanhf(d + bp[0]);
  }
  __syncthreads();
  float t0 = wgt[tid], t1 = wgt[tid + 256];
  float m = fmaxf(t0, t1);
  #pragma unroll
  for (int off = 32; off > 0; off >>= 1) m = fmaxf(m, __shfl_xor(m, off));
  if (lane == 0) red[wave] = m;
  __syncthreads();
  m = fmaxf(fmaxf(red[0], red[1]), fmaxf(red[2], red[3]));
  float e0 = __expf(t0 - m), e1 = __expf(t1 - m);
  float ssum = e0 + e1;
  #pragma unroll
  for (int off = 32; off > 0; off >>= 1) ssum += __shfl_xor(ssum, off);
  if (lane == 0) red[4 + wave] = ssum;
  __syncthreads();
  float invS = 1.f / (red[4] + red[5] + red[6] + red[7]);
  wgt[tid] = e0 * invS;
  wgt[tid + 256] = e1 * invS;
  __syncthreads();
  float acc = 0.f;
  #pragma unroll 8
  for (int n = 0; n < N_; n++) acc += wgt[n] * xb[(size_t)n * E_ + tid];
  out[b * E_ + tid] = acc;
}

// ---------------- launch ----------------
extern "C" void kernel_launch(void* const* d_in, const int* in_sizes, int n_in,
                              void* d_out, int out_size, void* d_ws, size_t ws_size,
                              hipStream_t stream) {
  (void)in_sizes; (void)n_in; (void)out_size; (void)ws_size;
  const float* x      = (const float*)d_in[0];
  const float* adj    = (const float*)d_in[1];
  const float* emb    = (const float*)d_in[2];
  const float* w_qkv  = (const float*)d_in[3];
  const float* b_qkv  = (const float*)d_in[4];
  const float* w_out  = (const float*)d_in[5];
  const float* b_out  = (const float*)d_in[6];
  const float* w_ff1  = (const float*)d_in[7];
  const float* b_ff1  = (const float*)d_in[8];
  const float* w_ff2  = (const float*)d_in[9];
  const float* b_ff2  = (const float*)d_in[10];
  const float* g1     = (const float*)d_in[11];
  const float* be1    = (const float*)d_in[12];
  const float* g2     = (const float*)d_in[13];
  const float* be2    = (const float*)d_in[14];
  const float* w_pool = (const float*)d_in[15];
  const float* b_pool = (const float*)d_in[16];

  char* ws = (char*)d_ws;
  // layout (bytes): bits 256K | region A 16M (qkv 12.58M + ctx 4.19M; hff reuses A) | t 4M | x1 4M | x2 4M
  unsigned int* bits = (unsigned int*)ws;
  float* qkv  = (float*)(ws + (size_t)262144);
  float* ctx  = (float*)(ws + (size_t)262144 + 12582912);
  float* hff  = qkv;  // 16777216 bytes, reused after attention+out-proj
  float* tbuf = (float*)(ws + (size_t)262144 + 16777216);
  float* x1   = tbuf + 1048576;
  float* x2   = x1 + 1048576;
  float* outp = (float*)d_out;

  const int M = B_ * N_;  // 4096

  topk_kernel<<<B_ * N_, 256, 0, stream>>>(adj, bits);
  gemm_bt_kernel<<<dim3(768 / 64, M / 64), 256, 0, stream>>>(
      x, w_qkv, b_qkv, nullptr, qkv, M, 768, E_, 0);
  flash_attn_kernel<<<B_ * H_ * (N_ / 64), 256, 0, stream>>>(qkv, bits, emb, ctx);
  gemm_bt_kernel<<<dim3(E_ / 64, M / 64), 256, 0, stream>>>(
      ctx, w_out, b_out, x, tbuf, M, E_, E_, 0);
  layernorm_kernel<<<M, 256, 0, stream>>>(tbuf, g1, be1, x1);
  gemm_bt_kernel<<<dim3(1024 / 64, M / 64), 256, 0, stream>>>(
      x1, w_ff1, b_ff1, nullptr, hff, M, 1024, E_, 1);
  gemm_bt_kernel<<<dim3(E_ / 64, M / 64), 256, 0, stream>>>(
      hff, w_ff2, b_ff2, x1, tbuf, M, E_, 1024, 0);
  layernorm_kernel<<<M, 256, 0, stream>>>(tbuf, g2, be2, x2);
  pool_kernel<<<B_, 256, 0, stream>>>(x2, w_pool, b_pool, outp);
}

// Round 2
// 424.944 us; speedup vs baseline: 1.2802x; 1.2802x over previous
//
#include <hip/hip_runtime.h>
#include <math.h>

// SubGraphTransformer: B=8,N=512,E=256,H=8,HD=32,FF=1024,TOPK=102.
// KEY INSIGHT: Floyd-Warshall is dead code. Mask = -inf where binary==0; on
// surviving (binary==1) entries dist==1 (direct edge) except diagonal (dist==0).
// Row-constant bias emb[2][h] cancels under softmax; only the diagonal delta
// emb[1][h]-emb[2][h] survives. So we need only the top-k bitmask + delta_h.

#define B_ 8
#define N_ 512
#define E_ 256
#define H_ 8
#define HD_ 32
#define TOPK_ 102

// ---------------- 1. top-k(102) per row -> 512-bit mask ----------------
// R2: histogram select + ballot mask write + parallel candidate rank.
// (R1's per-candidate serial 512-iter LDS scan was 138us = top dispatch.)
__global__ __launch_bounds__(256) void topk_kernel(const float* __restrict__ adj,
                                                   unsigned int* __restrict__ bits) {
  const int row = blockIdx.x;  // b*N + i
  const float* a = adj + (size_t)row * N_;
  __shared__ unsigned int hist[1024];
  __shared__ float cval[N_];
  __shared__ int cidx[N_];
  __shared__ int s_cnt;
  __shared__ int s_bb;
  __shared__ int s_need;
  __shared__ unsigned int rowbits[16];
  __shared__ int wsum[4];
  const int t = threadIdx.x;
  const int lane = t & 63;
  const int wave = t >> 6;

  hist[t] = 0u; hist[t + 256] = 0u; hist[t + 512] = 0u; hist[t + 768] = 0u;
  if (t == 0) s_cnt = 0;
  float v0 = a[t];
  float v1 = a[t + 256];
  __syncthreads();
  // values uniform [0,1): v*1024 exact (pow2 scale); floor via int cast
  const int b0 = min(1023, max(0, (int)(v0 * 1024.0f)));
  const int b1 = min(1023, max(0, (int)(v1 * 1024.0f)));
  atomicAdd(&hist[b0], 1u);
  atomicAdd(&hist[b1], 1u);
  __syncthreads();
  // thread t owns 4 buckets counting down from the top; scan in t-order
  const int base = 1020 - 4 * t;
  const int h0 = (int)hist[base], h1 = (int)hist[base + 1];
  const int h2 = (int)hist[base + 2], h3 = (int)hist[base + 3];
  const int g = h0 + h1 + h2 + h3;
  int sc = g;  // wave-level inclusive scan (no barriers)
  #pragma unroll
  for (int off = 1; off < 64; off <<= 1) {
    int y = __shfl_up(sc, off);
    sc += (lane >= off) ? y : 0;
  }
  if (lane == 63) wsum[wave] = sc;
  __syncthreads();
  int wo = 0;
  for (int w = 0; w < wave; w++) wo += wsum[w];
  const int incl = sc + wo;
  const int excl = incl - g;
  if (excl < TOPK_ && incl >= TOPK_) {  // exactly one thread
    int cum = excl;
    int bb = base;
    const int hh[4] = {h3, h2, h1, h0};            // descending bucket order
    const int bs[4] = {base + 3, base + 2, base + 1, base};
    #pragma unroll
    for (int u = 0; u < 4; u++) {
      if (cum + hh[u] >= TOPK_) { bb = bs[u]; break; }
      cum += hh[u];
    }
    s_bb = bb;
    s_need = TOPK_ - cum;
  }
  __syncthreads();
  const int bb = s_bb;
  const int need = s_need;
  const bool sel0 = (b0 > bb);
  const bool sel1 = (b1 > bb);
  if (b0 == bb) { int p = atomicAdd(&s_cnt, 1); cval[p] = v0; cidx[p] = t; }
  if (b1 == bb) { int p = atomicAdd(&s_cnt, 1); cval[p] = v1; cidx[p] = t + 256; }
  unsigned long long m0 = __ballot(sel0);   // bit `lane` = idx wave*64+lane
  unsigned long long m1 = __ballot(sel1);   // bit `lane` = idx 256+wave*64+lane
  if (lane == 0) {
    rowbits[2 * wave + 0] = (unsigned int)m0;
    rowbits[2 * wave + 1] = (unsigned int)(m0 >> 32);
    rowbits[8 + 2 * wave + 0] = (unsigned int)m1;
    rowbits[8 + 2 * wave + 1] = (unsigned int)(m1 >> 32);
  }
  __syncthreads();
  const int cnt = s_cnt;
  // rank boundary candidates in parallel: exact jax order (value desc, idx asc)
  for (int c = t; c < cnt; c += 256) {
    const float v = cval[c];
    const int idx = cidx[c];
    int r = 0;
    for (int j = 0; j < cnt; j++) {
      const float vj = cval[j];
      const int ij = cidx[j];
      if (vj > v || (vj == v && ij < idx)) r++;
    }
    if (r < need) atomicOr(&rowbits[idx >> 5], 1u << (idx & 31));
  }
  __syncthreads();
  if (t < 16) bits[(size_t)row * 16 + t] = rowbits[t];
}

// ---------------- 2. fp32 GEMM: C[M,N] = A[M,K] * B[N,K]^T + bias (+res)(relu)
__global__ __launch_bounds__(256) void gemm_bt_kernel(
    const float* __restrict__ A, const float* __restrict__ Bw,
    const float* __restrict__ bias, const float* __restrict__ res,
    float* __restrict__ C, int M, int N, int K, int relu) {
  __shared__ float As[16][68];
  __shared__ float Bs[16][68];
  const int tid = threadIdx.x;
  const int tx = tid & 15;
  const int ty = tid >> 4;
  const int m0 = blockIdx.y * 64;
  const int n0 = blockIdx.x * 64;
  const int lrow = tid >> 2;        // 0..63
  const int lk4 = (tid & 3) * 4;    // 0,4,8,12
  const float* Ap = A + (size_t)(m0 + lrow) * K + lk4;
  const float* Bp = Bw + (size_t)(n0 + lrow) * K + lk4;
  float acc[4][4] = {{0.f, 0.f, 0.f, 0.f}, {0.f, 0.f, 0.f, 0.f},
                     {0.f, 0.f, 0.f, 0.f}, {0.f, 0.f, 0.f, 0.f}};
  for (int k0 = 0; k0 < K; k0 += 16) {
    float4 av = *(const float4*)(Ap + k0);
    float4 bv = *(const float4*)(Bp + k0);
    __syncthreads();
    As[lk4 + 0][lrow] = av.x;
    As[lk4 + 1][lrow] = av.y;
    As[lk4 + 2][lrow] = av.z;
    As[lk4 + 3][lrow] = av.w;
    Bs[lk4 + 0][lrow] = bv.x;
    Bs[lk4 + 1][lrow] = bv.y;
    Bs[lk4 + 2][lrow] = bv.z;
    Bs[lk4 + 3][lrow] = bv.w;
    __syncthreads();
    #pragma unroll
    for (int kk = 0; kk < 16; kk++) {
      float4 a4 = *(const float4*)&As[kk][ty * 4];
      float4 b4 = *(const float4*)&Bs[kk][tx * 4];
      float aa[4] = {a4.x, a4.y, a4.z, a4.w};
      float bb[4] = {b4.x, b4.y, b4.z, b4.w};
      #pragma unroll
      for (int i = 0; i < 4; i++)
        #pragma unroll
        for (int j = 0; j < 4; j++) acc[i][j] += aa[i] * bb[j];
    }
  }
  float4 bsv = *(const float4*)(bias + n0 + tx * 4);
  float bvv[4] = {bsv.x, bsv.y, bsv.z, bsv.w};
  #pragma unroll
  for (int i = 0; i < 4; i++) {
    int m = m0 + ty * 4 + i;
    float o[4];
    #pragma unroll
    for (int j = 0; j < 4; j++) o[j] = acc[i][j] + bvv[j];
    if (res) {
      float4 rv = *(const float4*)(res + (size_t)m * N + n0 + tx * 4);
      o[0] += rv.x; o[1] += rv.y; o[2] += rv.z; o[3] += rv.w;
    }
    if (relu) {
      #pragma unroll
      for (int j = 0; j < 4; j++) o[j] = fmaxf(o[j], 0.f);
    }
    float4 ov = make_float4(o[0], o[1], o[2], o[3]);
    *(float4*)(C + (size_t)m * N + n0 + tx * 4) = ov;
  }
}

// ---------------- 3. masked flash attention ----------------
// grid: b(8) x h(8) x i-block(8 of 64 rows); block 256 thr = 4 waves x 16 rows
__global__ __launch_bounds__(256, 2) void flash_attn_kernel(
    const float* __restrict__ qkv, const unsigned int* __restrict__ bits,
    const float* __restrict__ emb, float* __restrict__ ctxo) {
  const int bx = blockIdx.x;
  const int ib = bx & 7;
  const int h = (bx >> 3) & 7;
  const int b = bx >> 6;
  const int tid = threadIdx.x;
  const int lane = tid & 63;
  const int wave = __builtin_amdgcn_readfirstlane(tid >> 6);
  const int rr = lane >> 3;  // phase-C row pair 0..7
  const int dd = lane & 7;   // phase-C d-lane 0..7 (owns d = dd+8u)

  __shared__ float kT[32][68];      // kT[d][j]
  __shared__ float vT[32][68];      // vT[d][j]
  __shared__ float pS[4][16][68];   // per-wave P[r][j]

  const float delta = emb[1 * H_ + h] - emb[2 * H_ + h];
  const float scale = 0.17677669529663687f;  // 1/sqrt(32)

  float m_run[16], l_part[16];
  float cacc[2][4];
  #pragma unroll
  for (int r = 0; r < 16; r++) { m_run[r] = -1e30f; l_part[r] = 0.f; }
  #pragma unroll
  for (int e = 0; e < 2; e++)
    #pragma unroll
    for (int u = 0; u < 4; u++) cacc[e][u] = 0.f;

  const int sj = tid >> 2;  // staging row 0..63
  const int sc = tid & 3;   // staging chunk 0..3

  #pragma unroll 1
  for (int jt = 0; jt < 8; jt++) {
    __syncthreads();
    {  // stage k,v tiles transposed into LDS (coalesced global float4 reads)
      const float* krow = qkv + ((size_t)(b * N_ + jt * 64 + sj)) * 768 + E_ + h * HD_;
      float4 ka = *(const float4*)(krow + sc * 4);
      float4 kb = *(const float4*)(krow + sc * 4 + 16);
      const float* vrow = krow + E_;
      float4 va = *(const float4*)(vrow + sc * 4);
      float4 vb = *(const float4*)(vrow + sc * 4 + 16);
      kT[sc * 4 + 0][sj] = ka.x; kT[sc * 4 + 1][sj] = ka.y;
      kT[sc * 4 + 2][sj] = ka.z; kT[sc * 4 + 3][sj] = ka.w;
      kT[16 + sc * 4 + 0][sj] = kb.x; kT[16 + sc * 4 + 1][sj] = kb.y;
      kT[16 + sc * 4 + 2][sj] = kb.z; kT[16 + sc * 4 + 3][sj] = kb.w;
      vT[sc * 4 + 0][sj] = va.x; vT[sc * 4 + 1][sj] = va.y;
      vT[sc * 4 + 2][sj] = va.z; vT[sc * 4 + 3][sj] = va.w;
      vT[16 + sc * 4 + 0][sj] = vb.x; vT[16 + sc * 4 + 1][sj] = vb.y;
      vT[16 + sc * 4 + 2][sj] = vb.z; vT[16 + sc * 4 + 3][sj] = vb.w;
    }
    __syncthreads();
    // lane caches its k column (j = jt*64+lane) in VGPRs; bank = (4d+lane)%32 ok
    float kreg[32];
    #pragma unroll
    for (int d = 0; d < 32; d++) kreg[d] = kT[d][lane];

    float a0 = 1.f, a1 = 1.f;
    #pragma unroll
    for (int r = 0; r < 16; r++) {
      const int ig = ib * 64 + wave * 16 + r;
      const float* qrow = qkv + ((size_t)(b * N_ + ig)) * 768 + h * HD_;  // uniform -> s_load
      float s = 0.f;
      #pragma unroll
      for (int d4 = 0; d4 < 8; d4++) {
        float4 q4 = *(const float4*)(qrow + d4 * 4);
        s += q4.x * kreg[d4 * 4 + 0] + q4.y * kreg[d4 * 4 + 1] +
             q4.z * kreg[d4 * 4 + 2] + q4.w * kreg[d4 * 4 + 3];
      }
      s *= scale;
      unsigned int wb = bits[((size_t)(b * N_ + ig)) * 16 + jt * 2 + (lane >> 5)];
      bool allowed = ((wb >> (lane & 31)) & 1u) != 0u;
      int jg = jt * 64 + lane;
      s = allowed ? (s + ((jg == ig) ? delta : 0.f)) : -INFINITY;
      // online softmax (row max across 64 j-lanes)
      float mt = s;
      #pragma unroll
      for (int off = 1; off < 64; off <<= 1) mt = fmaxf(mt, __shfl_xor(mt, off));
      float mnew = fmaxf(m_run[r], mt);
      float al = __expf(m_run[r] - mnew);
      m_run[r] = mnew;
      float p = __expf(s - mnew);
      l_part[r] = l_part[r] * al + p;
      pS[wave][r][lane] = p;
      a0 = (r == 2 * rr) ? al : a0;
      a1 = (r == 2 * rr + 1) ? al : a1;
    }
    // phase C: ctx[r][d] += sum_j P[r][j] * v[j][d]
    #pragma unroll
    for (int u = 0; u < 4; u++) { cacc[0][u] *= a0; cacc[1][u] *= a1; }
    #pragma unroll
    for (int jq = 0; jq < 16; jq++) {
      float4 p0 = *(const float4*)&pS[wave][2 * rr][jq * 4];
      float4 p1 = *(const float4*)&pS[wave][2 * rr + 1][jq * 4];
      #pragma unroll
      for (int u = 0; u < 4; u++) {
        float4 v4 = *(const float4*)&vT[dd + 8 * u][jq * 4];  // banks 4dd+4jq: conflict-free
        cacc[0][u] += p0.x * v4.x + p0.y * v4.y + p0.z * v4.z + p0.w * v4.w;
        cacc[1][u] += p1.x * v4.x + p1.y * v4.y + p1.z * v4.z + p1.w * v4.w;
      }
    }
  }
  // finalize: row sums l, normalize, store ctx[b][i][h*32+d]
  float linv0 = 1.f, linv1 = 1.f;
  #pragma unroll
  for (int r = 0; r < 16; r++) {
    float lv = l_part[r];
    #pragma unroll
    for (int off = 1; off < 64; off <<= 1) lv += __shfl_xor(lv, off);
    if (r == 2 * rr) linv0 = 1.f / lv;
    if (r == 2 * rr + 1) linv1 = 1.f / lv;
  }
  const int i0 = ib * 64 + wave * 16 + 2 * rr;
  float* c0 = ctxo + ((size_t)(b * N_ + i0)) * E_ + h * HD_ + dd;
  #pragma unroll
  for (int u = 0; u < 4; u++) {
    c0[8 * u] = cacc[0][u] * linv0;
    c0[E_ + 8 * u] = cacc[1][u] * linv1;
  }
}

// ---------------- 4. LayerNorm over E=256 ----------------
__global__ __launch_bounds__(256) void layernorm_kernel(
    const float* __restrict__ t, const float* __restrict__ g,
    const float* __restrict__ be, float* __restrict__ out) {
  const int row = blockIdx.x;
  const int tid = threadIdx.x;
  float v = t[(size_t)row * E_ + tid];
  float s = v, s2 = v * v;
  #pragma unroll
  for (int off = 32; off > 0; off >>= 1) {
    s += __shfl_xor(s, off);
    s2 += __shfl_xor(s2, off);
  }
  __shared__ float sh[8];
  const int wave = tid >> 6, lane = tid & 63;
  if (lane == 0) { sh[wave] = s; sh[4 + wave] = s2; }
  __syncthreads();
  s = sh[0] + sh[1] + sh[2] + sh[3];
  s2 = sh[4] + sh[5] + sh[6] + sh[7];
  float mean = s * (1.f / 256.f);
  float var = s2 * (1.f / 256.f) - mean * mean;
  float inv = rsqrtf(var + 1e-5f);
  out[(size_t)row * E_ + tid] = (v - mean) * inv * g[tid] + be[tid];
}

// ---------------- 5. attention pooling ----------------
__global__ __launch_bounds__(256) void pool_kernel(
    const float* __restrict__ x2, const float* __restrict__ wp,
    const float* __restrict__ bp, float* __restrict__ out) {
  const int b = blockIdx.x;
  const int tid = threadIdx.x;
  const int wave = tid >> 6, lane = tid & 63;
  __shared__ float wgt[N_];
  __shared__ float red[8];
  const float* xb = x2 + (size_t)b * N_ * E_;
  float4 wv = *(const float4*)(wp + lane * 4);
  for (int n = wave; n < N_; n += 4) {
    float4 xv = *(const float4*)(xb + (size_t)n * E_ + lane * 4);
    float d = xv.x * wv.x + xv.y * wv.y + xv.z * wv.z + xv.w * wv.w;
    #pragma unroll
    for (int off = 32; off > 0; off >>= 1) d += __shfl_xor(d, off);
    if (lane == 0) wgt[n] = tanhf(d + bp[0]);
  }
  __syncthreads();
  float t0 = wgt[tid], t1 = wgt[tid + 256];
  float m = fmaxf(t0, t1);
  #pragma unroll
  for (int off = 32; off > 0; off >>= 1) m = fmaxf(m, __shfl_xor(m, off));
  if (lane == 0) red[wave] = m;
  __syncthreads();
  m = fmaxf(fmaxf(red[0], red[1]), fmaxf(red[2], red[3]));
  float e0 = __expf(t0 - m), e1 = __expf(t1 - m);
  float ssum = e0 + e1;
  #pragma unroll
  for (int off = 32; off > 0; off >>= 1) ssum += __shfl_xor(ssum, off);
  if (lane == 0) red[4 + wave] = ssum;
  __syncthreads();
  float invS = 1.f / (red[4] + red[5] + red[6] + red[7]);
  wgt[tid] = e0 * invS;
  wgt[tid + 256] = e1 * invS;
  __syncthreads();
  float acc = 0.f;
  #pragma unroll 8
  for (int n = 0; n < N_; n++) acc += wgt[n] * xb[(size_t)n * E_ + tid];
  out[b * E_ + tid] = acc;
}

// ---------------- launch ----------------
extern "C" void kernel_launch(void* const* d_in, const int* in_sizes, int n_in,
                              void* d_out, int out_size, void* d_ws, size_t ws_size,
                              hipStream_t stream) {
  (void)in_sizes; (void)n_in; (void)out_size; (void)ws_size;
  const float* x      = (const float*)d_in[0];
  const float* adj    = (const float*)d_in[1];
  const float* emb    = (const float*)d_in[2];
  const float* w_qkv  = (const float*)d_in[3];
  const float* b_qkv  = (const float*)d_in[4];
  const float* w_out  = (const float*)d_in[5];
  const float* b_out  = (const float*)d_in[6];
  const float* w_ff1  = (const float*)d_in[7];
  const float* b_ff1  = (const float*)d_in[8];
  const float* w_ff2  = (const float*)d_in[9];
  const float* b_ff2  = (const float*)d_in[10];
  const float* g1     = (const float*)d_in[11];
  const float* be1    = (const float*)d_in[12];
  const float* g2     = (const float*)d_in[13];
  const float* be2    = (const float*)d_in[14];
  const float* w_pool = (const float*)d_in[15];
  const float* b_pool = (const float*)d_in[16];

  char* ws = (char*)d_ws;
  // layout (bytes): bits 256K | region A 16M (qkv 12.58M + ctx 4.19M; hff reuses A) | t 4M | x1 4M | x2 4M
  unsigned int* bits = (unsigned int*)ws;
  float* qkv  = (float*)(ws + (size_t)262144);
  float* ctx  = (float*)(ws + (size_t)262144 + 12582912);
  float* hff  = qkv;  // 16777216 bytes, reused after attention+out-proj
  float* tbuf = (float*)(ws + (size_t)262144 + 16777216);
  float* x1   = tbuf + 1048576;
  float* x2   = x1 + 1048576;
  float* outp = (float*)d_out;

  const int M = B_ * N_;  // 4096

  topk_kernel<<<B_ * N_, 256, 0, stream>>>(adj, bits);
  gemm_bt_kernel<<<dim3(768 / 64, M / 64), 256, 0, stream>>>(
      x, w_qkv, b_qkv, nullptr, qkv, M, 768, E_, 0);
  flash_attn_kernel<<<B_ * H_ * (N_ / 64), 256, 0, stream>>>(qkv, bits, emb, ctx);
  gemm_bt_kernel<<<dim3(E_ / 64, M / 64), 256, 0, stream>>>(
      ctx, w_out, b_out, x, tbuf, M, E_, E_, 0);
  layernorm_kernel<<<M, 256, 0, stream>>>(tbuf, g1, be1, x1);
  gemm_bt_kernel<<<dim3(1024 / 64, M / 64), 256, 0, stream>>>(
      x1, w_ff1, b_ff1, nullptr, hff, M, 1024, E_, 1);
  gemm_bt_kernel<<<dim3(E_ / 64, M / 64), 256, 0, stream>>>(
      hff, w_ff2, b_ff2, x1, tbuf, M, E_, 1024, 0);
  layernorm_kernel<<<M, 256, 0, stream>>>(tbuf, g2, be2, x2);
  pool_kernel<<<B_, 256, 0, stream>>>(x2, w_pool, b_pool, outp);
}

// Round 3
// 257.680 us; speedup vs baseline: 2.1112x; 1.6491x over previous
//
#include <hip/hip_runtime.h>
#include <math.h>

// SubGraphTransformer: B=8,N=512,E=256,H=8,HD=32,FF=1024,TOPK=102.
// Floyd-Warshall is dead code: surviving (top-k) entries all have dist==1
// except the diagonal (dist==0); row-constant bias cancels under softmax, so
// only topk bitmask + per-head diagonal delta (emb[1][h]-emb[2][h]) matter.
// R3: all heavy math in bf16 MFMA (16x16x32), fp32 accum/softmax/LN/residual.

#define B_ 8
#define N_ 512
#define E_ 256
#define H_ 8
#define HD_ 32
#define TOPK_ 102

typedef __attribute__((ext_vector_type(8))) short bf16x8;
typedef __attribute__((ext_vector_type(4))) float f32x4;

__device__ __forceinline__ unsigned short f2b(float f) {  // fp32->bf16 RNE
  unsigned u = __builtin_bit_cast(unsigned, f);
  return (unsigned short)((u + 0x7FFFu + ((u >> 16) & 1u)) >> 16);
}

// ---------------- 0. fp32 -> bf16 cast ----------------
__global__ __launch_bounds__(256) void cvt_kernel(const float* __restrict__ src,
                                                  unsigned short* __restrict__ dst, int n) {
  int i = (blockIdx.x * 256 + threadIdx.x) * 4;
  if (i < n) {
    float4 v = *(const float4*)(src + i);
    ushort4 o;
    o.x = f2b(v.x); o.y = f2b(v.y); o.z = f2b(v.z); o.w = f2b(v.w);
    *(ushort4*)(dst + i) = o;
  }
}

// ---------------- 1. top-k(102) per row -> 512-bit mask ----------------
__global__ __launch_bounds__(256) void topk_kernel(const float* __restrict__ adj,
                                                   unsigned int* __restrict__ bits) {
  const int row = blockIdx.x;  // b*N + i
  const float* a = adj + (size_t)row * N_;
  __shared__ unsigned int hist[1024];
  __shared__ float cval[N_];
  __shared__ int cidx[N_];
  __shared__ int s_cnt;
  __shared__ int s_bb;
  __shared__ int s_need;
  __shared__ unsigned int rowbits[16];
  __shared__ int wsum[4];
  const int t = threadIdx.x;
  const int lane = t & 63;
  const int wave = t >> 6;

  hist[t] = 0u; hist[t + 256] = 0u; hist[t + 512] = 0u; hist[t + 768] = 0u;
  if (t == 0) s_cnt = 0;
  float v0 = a[t];
  float v1 = a[t + 256];
  __syncthreads();
  const int b0 = min(1023, max(0, (int)(v0 * 1024.0f)));
  const int b1 = min(1023, max(0, (int)(v1 * 1024.0f)));
  atomicAdd(&hist[b0], 1u);
  atomicAdd(&hist[b1], 1u);
  __syncthreads();
  const int base = 1020 - 4 * t;
  const int h0 = (int)hist[base], h1 = (int)hist[base + 1];
  const int h2 = (int)hist[base + 2], h3 = (int)hist[base + 3];
  const int g = h0 + h1 + h2 + h3;
  int sc = g;
  #pragma unroll
  for (int off = 1; off < 64; off <<= 1) {
    int y = __shfl_up(sc, off);
    sc += (lane >= off) ? y : 0;
  }
  if (lane == 63) wsum[wave] = sc;
  __syncthreads();
  int wo = 0;
  for (int w = 0; w < wave; w++) wo += wsum[w];
  const int incl = sc + wo;
  const int excl = incl - g;
  if (excl < TOPK_ && incl >= TOPK_) {
    int cum = excl;
    int bb = base;
    const int hh[4] = {h3, h2, h1, h0};
    const int bs[4] = {base + 3, base + 2, base + 1, base};
    #pragma unroll
    for (int u = 0; u < 4; u++) {
      if (cum + hh[u] >= TOPK_) { bb = bs[u]; break; }
      cum += hh[u];
    }
    s_bb = bb;
    s_need = TOPK_ - cum;
  }
  __syncthreads();
  const int bb = s_bb;
  const int need = s_need;
  const bool sel0 = (b0 > bb);
  const bool sel1 = (b1 > bb);
  if (b0 == bb) { int p = atomicAdd(&s_cnt, 1); cval[p] = v0; cidx[p] = t; }
  if (b1 == bb) { int p = atomicAdd(&s_cnt, 1); cval[p] = v1; cidx[p] = t + 256; }
  unsigned long long m0 = __ballot(sel0);
  unsigned long long m1 = __ballot(sel1);
  if (lane == 0) {
    rowbits[2 * wave + 0] = (unsigned int)m0;
    rowbits[2 * wave + 1] = (unsigned int)(m0 >> 32);
    rowbits[8 + 2 * wave + 0] = (unsigned int)m1;
    rowbits[8 + 2 * wave + 1] = (unsigned int)(m1 >> 32);
  }
  __syncthreads();
  const int cnt = s_cnt;
  for (int c = t; c < cnt; c += 256) {
    const float v = cval[c];
    const int idx = cidx[c];
    int r = 0;
    for (int j = 0; j < cnt; j++) {
      const float vj = cval[j];
      const int ij = cidx[j];
      if (vj > v || (vj == v && ij < idx)) r++;
    }
    if (r < need) atomicOr(&rowbits[idx >> 5], 1u << (idx & 31));
  }
  __syncthreads();
  if (t < 16) bits[(size_t)row * 16 + t] = rowbits[t];
}

// ---------------- 2. bf16 MFMA GEMM: C[M,N] = A[M,K]*W[N,K]^T + bias ----------------
// flags: 1=relu, 2=bf16 output. res (fp32) optional.
__global__ __launch_bounds__(256) void gemm_mfma(
    const unsigned short* __restrict__ A, const unsigned short* __restrict__ W,
    const float* __restrict__ bias, const float* __restrict__ res,
    void* __restrict__ Cout, int M, int N, int K, int flags) {
  __shared__ __align__(16) unsigned short Af[8 * 64 * 8];  // [mtile*2+kc][lane][8]
  __shared__ __align__(16) unsigned short Wf[8 * 64 * 8];
  const int tid = threadIdx.x;
  const int m0 = blockIdx.y * 64, n0 = blockIdx.x * 64;
  const int wave = tid >> 6, lane = tid & 63;
  const int wm = wave & 1, wn = wave >> 1;
  const int q = lane >> 4, l15 = lane & 15;
  const int r = tid >> 2, c0 = tid & 3;  // staging: row r, chunks c0, c0+4

  f32x4 acc[2][2];
  #pragma unroll
  for (int i = 0; i < 2; i++)
    #pragma unroll
    for (int j = 0; j < 2; j++) acc[i][j] = (f32x4){0.f, 0.f, 0.f, 0.f};

  const size_t arow = (size_t)(m0 + r) * K;
  const size_t wrow = (size_t)(n0 + r) * K;
  for (int k0 = 0; k0 < K; k0 += 64) {
    uint4 a0 = *(const uint4*)(A + arow + k0 + c0 * 8);
    uint4 a1 = *(const uint4*)(A + arow + k0 + (c0 + 4) * 8);
    uint4 w0 = *(const uint4*)(W + wrow + k0 + c0 * 8);
    uint4 w1 = *(const uint4*)(W + wrow + k0 + (c0 + 4) * 8);
    __syncthreads();
    // frag-order store: chunk c -> kc=c>>2, qq=c&3, slot=(r>>4)*2+kc, lane'=(r&15)+qq*16
    {
      int kc = c0 >> 2, qq = c0 & 3;
      int s0 = ((r >> 4) * 2 + kc) * 64 + (r & 15) + qq * 16;
      int kc1 = (c0 + 4) >> 2, qq1 = (c0 + 4) & 3;
      int s1 = ((r >> 4) * 2 + kc1) * 64 + (r & 15) + qq1 * 16;
      *(uint4*)(Af + s0 * 8) = a0;
      *(uint4*)(Af + s1 * 8) = a1;
      *(uint4*)(Wf + s0 * 8) = w0;
      *(uint4*)(Wf + s1 * 8) = w1;
    }
    __syncthreads();
    #pragma unroll
    for (int kc = 0; kc < 2; kc++) {
      bf16x8 af[2], wf[2];
      #pragma unroll
      for (int mt = 0; mt < 2; mt++)
        af[mt] = *(const bf16x8*)(Af + (((wm * 2 + mt) * 2 + kc) * 64 + lane) * 8);
      #pragma unroll
      for (int nt = 0; nt < 2; nt++)
        wf[nt] = *(const bf16x8*)(Wf + (((wn * 2 + nt) * 2 + kc) * 64 + lane) * 8);
      #pragma unroll
      for (int mt = 0; mt < 2; mt++)
        #pragma unroll
        for (int nt = 0; nt < 2; nt++)
          acc[mt][nt] = __builtin_amdgcn_mfma_f32_16x16x32_bf16(af[mt], wf[nt], acc[mt][nt], 0, 0, 0);
    }
  }
  // epilogue: C/D layout col=lane&15, row=q*4+reg
  #pragma unroll
  for (int nt = 0; nt < 2; nt++) {
    const int col = n0 + (wn * 2 + nt) * 16 + l15;
    const float bv = bias[col];
    #pragma unroll
    for (int mt = 0; mt < 2; mt++) {
      const int rowb = m0 + (wm * 2 + mt) * 16 + q * 4;
      #pragma unroll
      for (int reg = 0; reg < 4; reg++) {
        const int row = rowb + reg;
        float o = acc[mt][nt][reg] + bv;
        if (res) o += res[(size_t)row * N + col];
        if (flags & 1) o = fmaxf(o, 0.f);
        if (flags & 2) ((unsigned short*)Cout)[(size_t)row * N + col] = f2b(o);
        else           ((float*)Cout)[(size_t)row * N + col] = o;
      }
    }
  }
}

// ---------------- 3. masked flash attention, bf16 MFMA ----------------
// grid 512 = (b<<6)|(h<<3)|ib ; block 256 = 4 waves x 16 i-rows
__global__ __launch_bounds__(256) void attn_mfma(
    const unsigned short* __restrict__ qkv, const unsigned int* __restrict__ bits,
    const float* __restrict__ emb, unsigned short* __restrict__ ctxo) {
  const int bx = blockIdx.x;
  const int ib = bx & 7;
  const int h = (bx >> 3) & 7;
  const int b = bx >> 6;
  const int tid = threadIdx.x;
  const int lane = tid & 63;
  const int wave = tid >> 6;
  const int q = lane >> 4, l15 = lane & 15;

  __shared__ __align__(16) unsigned short kF[4 * 64 * 8];   // [jtile][lane][8] B-frags
  __shared__ __align__(16) unsigned short vF[4 * 64 * 8];   // [dt*2+kc][lane][8] B-frags
  __shared__ __align__(16) unsigned int mrow[64 * 16];      // mask words, 64 i-rows
  __shared__ __align__(16) unsigned short pF[4][2 * 64 * 8];// per-wave P A-frags

  // stage mask rows for this i-block (covered by first loop barrier)
  {
    int rr = tid >> 2, wq = tid & 3;
    uint4 mw = *(const uint4*)(bits + ((size_t)(b * N_ + ib * 64 + rr)) * 16 + wq * 4);
    *(uint4*)(mrow + rr * 16 + wq * 4) = mw;
  }
  // Q A-frag: lane holds Q[i0w + l15][q*8 .. q*8+7]  (16B contiguous)
  const int i0w = ib * 64 + wave * 16;
  const bf16x8 qf = *(const bf16x8*)(qkv + ((size_t)(b * N_ + i0w + l15)) * 768 + h * HD_ + q * 8);
  const float delta = emb[1 * H_ + h] - emb[2 * H_ + h];
  const float scale = 0.17677669529663687f;  // 1/sqrt(32)

  float m_run[4], l_run[4];
  #pragma unroll
  for (int e = 0; e < 4; e++) { m_run[e] = -1e30f; l_run[e] = 0.f; }
  f32x4 cacc[2];
  cacc[0] = (f32x4){0.f, 0.f, 0.f, 0.f};
  cacc[1] = (f32x4){0.f, 0.f, 0.f, 0.f};

  unsigned short* pbase = &pF[wave][0];
  const int sj = tid >> 2, scb = tid & 3;  // staging: row j=sj, d-chunk scb

  #pragma unroll 1
  for (int jt = 0; jt < 8; jt++) {
    __syncthreads();
    {  // stage K,V tiles into frag order
      const unsigned short* kvrow = qkv + ((size_t)(b * N_ + jt * 64 + sj)) * 768 + h * HD_;
      uint4 kv4 = *(const uint4*)(kvrow + E_ + scb * 8);
      *(uint4*)(kF + (((sj >> 4) * 64) + (sj & 15) + scb * 16) * 8) = kv4;
      uint4 vv4 = *(const uint4*)(kvrow + 2 * E_ + scb * 8);
      const unsigned short* vp = (const unsigned short*)&vv4;
      #pragma unroll
      for (int e2 = 0; e2 < 8; e2++) {  // scatter-transpose V
        int d = scb * 8 + e2;
        int slot = ((d >> 4) * 2 + (sj >> 5)) * 64 + (d & 15) + ((sj >> 3) & 3) * 16;
        vF[slot * 8 + (sj & 7)] = vp[e2];
      }
    }
    __syncthreads();
    // QK^T: 4 mfmas -> S[16 x 64]
    f32x4 s4[4];
    #pragma unroll
    for (int jtile = 0; jtile < 4; jtile++) {
      bf16x8 kf = *(const bf16x8*)(kF + (jtile * 64 + lane) * 8);
      s4[jtile] = __builtin_amdgcn_mfma_f32_16x16x32_bf16(qf, kf, (f32x4){0.f, 0.f, 0.f, 0.f}, 0, 0, 0);
    }
    // mask + diagonal delta
    unsigned long long mw64[4];
    #pragma unroll
    for (int reg = 0; reg < 4; reg++)
      mw64[reg] = *(const unsigned long long*)(mrow + (wave * 16 + q * 4 + reg) * 16 + jt * 2);
    float smat[4][4];
    #pragma unroll
    for (int jtile = 0; jtile < 4; jtile++) {
      #pragma unroll
      for (int reg = 0; reg < 4; reg++) {
        unsigned int w = (jtile & 2) ? (unsigned int)(mw64[reg] >> 32) : (unsigned int)mw64[reg];
        bool allowed = ((w >> ((jtile & 1) * 16 + l15)) & 1u) != 0u;
        int ig = ib * 64 + wave * 16 + q * 4 + reg;
        int jg = jt * 64 + jtile * 16 + l15;
        float s = s4[jtile][reg] * scale + ((jg == ig) ? delta : 0.f);
        smat[jtile][reg] = allowed ? s : -INFINITY;
      }
    }
    // online softmax per row (reduce over 16 lanes of the row-group)
    float alpha[4], pmat[4][4];
    #pragma unroll
    for (int reg = 0; reg < 4; reg++) {
      float mloc = fmaxf(fmaxf(smat[0][reg], smat[1][reg]), fmaxf(smat[2][reg], smat[3][reg]));
      #pragma unroll
      for (int off = 1; off < 16; off <<= 1) mloc = fmaxf(mloc, __shfl_xor(mloc, off));
      float mnew = fmaxf(m_run[reg], mloc);
      alpha[reg] = __expf(m_run[reg] - mnew);
      m_run[reg] = mnew;
      float ps = 0.f;
      #pragma unroll
      for (int jtile = 0; jtile < 4; jtile++) {
        float p = __expf(smat[jtile][reg] - mnew);
        pmat[jtile][reg] = p;
        ps += p;
      }
      #pragma unroll
      for (int off = 1; off < 16; off <<= 1) ps += __shfl_xor(ps, off);
      l_run[reg] = l_run[reg] * alpha[reg] + ps;
      cacc[0][reg] *= alpha[reg];
      cacc[1][reg] *= alpha[reg];
    }
    // P -> LDS (A-frag order, per-wave region; same-wave RAW, no barrier)
    #pragma unroll
    for (int jtile = 0; jtile < 4; jtile++) {
      int j_l = jtile * 16 + l15;
      int sl = ((j_l >> 5) * 64 + ((j_l >> 3) & 3) * 16) * 8 + (j_l & 7);
      #pragma unroll
      for (int reg = 0; reg < 4; reg++)
        pbase[sl + (q * 4 + reg) * 8] = f2b(pmat[jtile][reg]);
    }
    // PV: 4 mfmas
    #pragma unroll
    for (int kc = 0; kc < 2; kc++) {
      bf16x8 pf = *(const bf16x8*)(pbase + (kc * 64 + lane) * 8);
      #pragma unroll
      for (int dt = 0; dt < 2; dt++) {
        bf16x8 vf = *(const bf16x8*)(vF + ((dt * 2 + kc) * 64 + lane) * 8);
        cacc[dt] = __builtin_amdgcn_mfma_f32_16x16x32_bf16(pf, vf, cacc[dt], 0, 0, 0);
      }
    }
  }
  // finalize: ctx[b,i][h*32 + d] bf16
  #pragma unroll
  for (int reg = 0; reg < 4; reg++) {
    const float linv = 1.f / l_run[reg];
    const size_t row = (size_t)(b * N_ + i0w + q * 4 + reg);
    #pragma unroll
    for (int dt = 0; dt < 2; dt++)
      ctxo[row * E_ + h * HD_ + dt * 16 + l15] = f2b(cacc[dt][reg] * linv);
  }
}

// ---------------- 4. LayerNorm over E=256 (fp32 out + optional bf16 out) ----------------
__global__ __launch_bounds__(256) void layernorm_kernel(
    const float* __restrict__ t, const float* __restrict__ g,
    const float* __restrict__ be, float* __restrict__ out,
    unsigned short* __restrict__ outb) {
  const int row = blockIdx.x;
  const int tid = threadIdx.x;
  float v = t[(size_t)row * E_ + tid];
  float s = v, s2 = v * v;
  #pragma unroll
  for (int off = 32; off > 0; off >>= 1) {
    s += __shfl_xor(s, off);
    s2 += __shfl_xor(s2, off);
  }
  __shared__ float sh[8];
  const int wave = tid >> 6, lane = tid & 63;
  if (lane == 0) { sh[wave] = s; sh[4 + wave] = s2; }
  __syncthreads();
  s = sh[0] + sh[1] + sh[2] + sh[3];
  s2 = sh[4] + sh[5] + sh[6] + sh[7];
  float mean = s * (1.f / 256.f);
  float var = s2 * (1.f / 256.f) - mean * mean;
  float inv = rsqrtf(var + 1e-5f);
  float o = (v - mean) * inv * g[tid] + be[tid];
  out[(size_t)row * E_ + tid] = o;
  if (outb) outb[(size_t)row * E_ + tid] = f2b(o);
}

// ---------------- 5. attention pooling ----------------
__global__ __launch_bounds__(256) void pool_kernel(
    const float* __restrict__ x2, const float* __restrict__ wp,
    const float* __restrict__ bp, float* __restrict__ out) {
  const int b = blockIdx.x;
  const int tid = threadIdx.x;
  const int wave = tid >> 6, lane = tid & 63;
  __shared__ float wgt[N_];
  __shared__ float red[8];
  const float* xb = x2 + (size_t)b * N_ * E_;
  float4 wv = *(const float4*)(wp + lane * 4);
  for (int n = wave; n < N_; n += 4) {
    float4 xv = *(const float4*)(xb + (size_t)n * E_ + lane * 4);
    float d = xv.x * wv.x + xv.y * wv.y + xv.z * wv.z + xv.w * wv.w;
    #pragma unroll
    for (int off = 32; off > 0; off >>= 1) d += __shfl_xor(d, off);
    if (lane == 0) wgt[n] = tanhf(d + bp[0]);
  }
  __syncthreads();
  float t0 = wgt[tid], t1 = wgt[tid + 256];
  float m = fmaxf(t0, t1);
  #pragma unroll
  for (int off = 32; off > 0; off >>= 1) m = fmaxf(m, __shfl_xor(m, off));
  if (lane == 0) red[wave] = m;
  __syncthreads();
  m = fmaxf(fmaxf(red[0], red[1]), fmaxf(red[2], red[3]));
  float e0 = __expf(t0 - m), e1 = __expf(t1 - m);
  float ssum = e0 + e1;
  #pragma unroll
  for (int off = 32; off > 0; off >>= 1) ssum += __shfl_xor(ssum, off);
  if (lane == 0) red[4 + wave] = ssum;
  __syncthreads();
  float invS = 1.f / (red[4] + red[5] + red[6] + red[7]);
  wgt[tid] = e0 * invS;
  wgt[tid + 256] = e1 * invS;
  __syncthreads();
  float acc = 0.f;
  #pragma unroll 8
  for (int n = 0; n < N_; n++) acc += wgt[n] * xb[(size_t)n * E_ + tid];
  out[b * E_ + tid] = acc;
}

// ---------------- launch ----------------
extern "C" void kernel_launch(void* const* d_in, const int* in_sizes, int n_in,
                              void* d_out, int out_size, void* d_ws, size_t ws_size,
                              hipStream_t stream) {
  (void)in_sizes; (void)n_in; (void)out_size; (void)ws_size;
  const float* x      = (const float*)d_in[0];
  const float* adj    = (const float*)d_in[1];
  const float* emb    = (const float*)d_in[2];
  const float* w_qkv  = (const float*)d_in[3];
  const float* b_qkv  = (const float*)d_in[4];
  const float* w_out  = (const float*)d_in[5];
  const float* b_out  = (const float*)d_in[6];
  const float* w_ff1  = (const float*)d_in[7];
  const float* b_ff1  = (const float*)d_in[8];
  const float* w_ff2  = (const float*)d_in[9];
  const float* b_ff2  = (const float*)d_in[10];
  const float* g1     = (const float*)d_in[11];
  const float* be1    = (const float*)d_in[12];
  const float* g2     = (const float*)d_in[13];
  const float* be2    = (const float*)d_in[14];
  const float* w_pool = (const float*)d_in[15];
  const float* b_pool = (const float*)d_in[16];

  char* ws = (char*)d_ws;
  // byte layout (25.8 MB total; hffb reuses xb+qkvb region)
  unsigned int*   bits  = (unsigned int*)ws;                       // 256 KB
  unsigned short* xb    = (unsigned short*)(ws + 262144);          // 2 MB
  unsigned short* qkvb  = (unsigned short*)(ws + 2359296);         // 6 MB
  unsigned short* hffb  = xb;                                      // 8 MB reuse
  unsigned short* ctxb  = (unsigned short*)(ws + 8650752);         // 2 MB
  unsigned short* x1b   = (unsigned short*)(ws + 10747904);        // 2 MB
  unsigned short* wqkvb = (unsigned short*)(ws + 12845056);        // 384 KB
  unsigned short* woutb = (unsigned short*)(ws + 13238272);        // 128 KB
  unsigned short* wff1b = (unsigned short*)(ws + 13369344);        // 512 KB
  unsigned short* wff2b = (unsigned short*)(ws + 13893632);        // 512 KB
  float*          tbuf  = (float*)(ws + 14417920);                 // 4 MB
  float*          x1    = (float*)(ws + 18612224);                 // 4 MB
  float*          x2    = (float*)(ws + 22806528);                 // 4 MB
  float*          outp  = (float*)d_out;

  const int M = B_ * N_;  // 4096

  cvt_kernel<<<1048576 / 1024, 256, 0, stream>>>(x, xb, 1048576);
  cvt_kernel<<<196608 / 1024, 256, 0, stream>>>(w_qkv, wqkvb, 196608);
  cvt_kernel<<<65536 / 1024, 256, 0, stream>>>(w_out, woutb, 65536);
  cvt_kernel<<<262144 / 1024, 256, 0, stream>>>(w_ff1, wff1b, 262144);
  cvt_kernel<<<262144 / 1024, 256, 0, stream>>>(w_ff2, wff2b, 262144);
  topk_kernel<<<B_ * N_, 256, 0, stream>>>(adj, bits);
  gemm_mfma<<<dim3(768 / 64, M / 64), 256, 0, stream>>>(
      xb, wqkvb, b_qkv, nullptr, qkvb, M, 768, E_, 2);
  attn_mfma<<<B_ * H_ * (N_ / 64), 256, 0, stream>>>(qkvb, bits, emb, ctxb);
  gemm_mfma<<<dim3(E_ / 64, M / 64), 256, 0, stream>>>(
      ctxb, woutb, b_out, x, tbuf, M, E_, E_, 0);
  layernorm_kernel<<<M, 256, 0, stream>>>(tbuf, g1, be1, x1, x1b);
  gemm_mfma<<<dim3(1024 / 64, M / 64), 256, 0, stream>>>(
      x1b, wff1b, b_ff1, nullptr, hffb, M, 1024, E_, 1 | 2);
  gemm_mfma<<<dim3(E_ / 64, M / 64), 256, 0, stream>>>(
      hffb, wff2b, b_ff2, x1, tbuf, M, E_, 1024, 0);
  layernorm_kernel<<<M, 256, 0, stream>>>(tbuf, g2, be2, x2, nullptr);
  pool_kernel<<<B_, 256, 0, stream>>>(x2, w_pool, b_pool, outp);
}

// Round 4
// 179.834 us; speedup vs baseline: 3.0251x; 1.4329x over previous
//
#include <hip/hip_runtime.h>
#include <math.h>

// SubGraphTransformer: B=8,N=512,E=256,H=8,HD=32,FF=1024,TOPK=102.
// Floyd-Warshall is dead code: surviving (top-k) entries all have dist==1
// except the diagonal (dist==0); row-constant bias cancels under softmax, so
// only topk bitmask + per-head diagonal delta (emb[1][h]-emb[2][h]) matter.
// R3: all heavy math in bf16 MFMA (16x16x32), fp32 accum/softmax/LN/residual.
// R4: pool split into 256-block partial + tiny final (was 8-block latency
// disaster, 79us); pool weights fused into LN2 (tanh in [-1,1] -> softmax
// without max-subtraction is safe); 5 cvt launches fused into 1.

#define B_ 8
#define N_ 512
#define E_ 256
#define H_ 8
#define HD_ 32
#define TOPK_ 102

typedef __attribute__((ext_vector_type(8))) short bf16x8;
typedef __attribute__((ext_vector_type(4))) float f32x4;

__device__ __forceinline__ unsigned short f2b(float f) {  // fp32->bf16 RNE
  unsigned u = __builtin_bit_cast(unsigned, f);
  return (unsigned short)((u + 0x7FFFu + ((u >> 16) & 1u)) >> 16);
}

// ---------------- 0. fused fp32 -> bf16 cast of x + 4 weight mats ----------------
__global__ __launch_bounds__(256) void cvt_all(
    const float* __restrict__ x, const float* __restrict__ wqkv,
    const float* __restrict__ wout, const float* __restrict__ wff1,
    const float* __restrict__ wff2, unsigned short* __restrict__ xb,
    unsigned short* __restrict__ wqkvb, unsigned short* __restrict__ woutb,
    unsigned short* __restrict__ wff1b, unsigned short* __restrict__ wff2b) {
  int i = (blockIdx.x * 256 + threadIdx.x) * 4;
  const float* src;
  unsigned short* dst;
  int off;
  if (i < 1048576)      { src = x;    dst = xb;    off = i; }
  else if (i < 1245184) { src = wqkv; dst = wqkvb; off = i - 1048576; }
  else if (i < 1310720) { src = wout; dst = woutb; off = i - 1245184; }
  else if (i < 1572864) { src = wff1; dst = wff1b; off = i - 1310720; }
  else                  { src = wff2; dst = wff2b; off = i - 1572864; }
  float4 v = *(const float4*)(src + off);
  ushort4 o;
  o.x = f2b(v.x); o.y = f2b(v.y); o.z = f2b(v.z); o.w = f2b(v.w);
  *(ushort4*)(dst + off) = o;
}

// ---------------- 1. top-k(102) per row -> 512-bit mask ----------------
__global__ __launch_bounds__(256) void topk_kernel(const float* __restrict__ adj,
                                                   unsigned int* __restrict__ bits) {
  const int row = blockIdx.x;  // b*N + i
  const float* a = adj + (size_t)row * N_;
  __shared__ unsigned int hist[1024];
  __shared__ float cval[N_];
  __shared__ int cidx[N_];
  __shared__ int s_cnt;
  __shared__ int s_bb;
  __shared__ int s_need;
  __shared__ unsigned int rowbits[16];
  __shared__ int wsum[4];
  const int t = threadIdx.x;
  const int lane = t & 63;
  const int wave = t >> 6;

  hist[t] = 0u; hist[t + 256] = 0u; hist[t + 512] = 0u; hist[t + 768] = 0u;
  if (t == 0) s_cnt = 0;
  float v0 = a[t];
  float v1 = a[t + 256];
  __syncthreads();
  const int b0 = min(1023, max(0, (int)(v0 * 1024.0f)));
  const int b1 = min(1023, max(0, (int)(v1 * 1024.0f)));
  atomicAdd(&hist[b0], 1u);
  atomicAdd(&hist[b1], 1u);
  __syncthreads();
  const int base = 1020 - 4 * t;
  const int h0 = (int)hist[base], h1 = (int)hist[base + 1];
  const int h2 = (int)hist[base + 2], h3 = (int)hist[base + 3];
  const int g = h0 + h1 + h2 + h3;
  int sc = g;
  #pragma unroll
  for (int off = 1; off < 64; off <<= 1) {
    int y = __shfl_up(sc, off);
    sc += (lane >= off) ? y : 0;
  }
  if (lane == 63) wsum[wave] = sc;
  __syncthreads();
  int wo = 0;
  for (int w = 0; w < wave; w++) wo += wsum[w];
  const int incl = sc + wo;
  const int excl = incl - g;
  if (excl < TOPK_ && incl >= TOPK_) {
    int cum = excl;
    int bb = base;
    const int hh[4] = {h3, h2, h1, h0};
    const int bs[4] = {base + 3, base + 2, base + 1, base};
    #pragma unroll
    for (int u = 0; u < 4; u++) {
      if (cum + hh[u] >= TOPK_) { bb = bs[u]; break; }
      cum += hh[u];
    }
    s_bb = bb;
    s_need = TOPK_ - cum;
  }
  __syncthreads();
  const int bb = s_bb;
  const int need = s_need;
  const bool sel0 = (b0 > bb);
  const bool sel1 = (b1 > bb);
  if (b0 == bb) { int p = atomicAdd(&s_cnt, 1); cval[p] = v0; cidx[p] = t; }
  if (b1 == bb) { int p = atomicAdd(&s_cnt, 1); cval[p] = v1; cidx[p] = t + 256; }
  unsigned long long m0 = __ballot(sel0);
  unsigned long long m1 = __ballot(sel1);
  if (lane == 0) {
    rowbits[2 * wave + 0] = (unsigned int)m0;
    rowbits[2 * wave + 1] = (unsigned int)(m0 >> 32);
    rowbits[8 + 2 * wave + 0] = (unsigned int)m1;
    rowbits[8 + 2 * wave + 1] = (unsigned int)(m1 >> 32);
  }
  __syncthreads();
  const int cnt = s_cnt;
  for (int c = t; c < cnt; c += 256) {
    const float v = cval[c];
    const int idx = cidx[c];
    int r = 0;
    for (int j = 0; j < cnt; j++) {
      const float vj = cval[j];
      const int ij = cidx[j];
      if (vj > v || (vj == v && ij < idx)) r++;
    }
    if (r < need) atomicOr(&rowbits[idx >> 5], 1u << (idx & 31));
  }
  __syncthreads();
  if (t < 16) bits[(size_t)row * 16 + t] = rowbits[t];
}

// ---------------- 2. bf16 MFMA GEMM: C[M,N] = A[M,K]*W[N,K]^T + bias ----------------
// flags: 1=relu, 2=bf16 output. res (fp32) optional.
__global__ __launch_bounds__(256) void gemm_mfma(
    const unsigned short* __restrict__ A, const unsigned short* __restrict__ W,
    const float* __restrict__ bias, const float* __restrict__ res,
    void* __restrict__ Cout, int M, int N, int K, int flags) {
  __shared__ __align__(16) unsigned short Af[8 * 64 * 8];  // [mtile*2+kc][lane][8]
  __shared__ __align__(16) unsigned short Wf[8 * 64 * 8];
  const int tid = threadIdx.x;
  const int m0 = blockIdx.y * 64, n0 = blockIdx.x * 64;
  const int wave = tid >> 6, lane = tid & 63;
  const int wm = wave & 1, wn = wave >> 1;
  const int q = lane >> 4, l15 = lane & 15;
  const int r = tid >> 2, c0 = tid & 3;  // staging: row r, chunks c0, c0+4

  f32x4 acc[2][2];
  #pragma unroll
  for (int i = 0; i < 2; i++)
    #pragma unroll
    for (int j = 0; j < 2; j++) acc[i][j] = (f32x4){0.f, 0.f, 0.f, 0.f};

  const size_t arow = (size_t)(m0 + r) * K;
  const size_t wrow = (size_t)(n0 + r) * K;
  for (int k0 = 0; k0 < K; k0 += 64) {
    uint4 a0 = *(const uint4*)(A + arow + k0 + c0 * 8);
    uint4 a1 = *(const uint4*)(A + arow + k0 + (c0 + 4) * 8);
    uint4 w0 = *(const uint4*)(W + wrow + k0 + c0 * 8);
    uint4 w1 = *(const uint4*)(W + wrow + k0 + (c0 + 4) * 8);
    __syncthreads();
    {
      int kc = c0 >> 2, qq = c0 & 3;
      int s0 = ((r >> 4) * 2 + kc) * 64 + (r & 15) + qq * 16;
      int kc1 = (c0 + 4) >> 2, qq1 = (c0 + 4) & 3;
      int s1 = ((r >> 4) * 2 + kc1) * 64 + (r & 15) + qq1 * 16;
      *(uint4*)(Af + s0 * 8) = a0;
      *(uint4*)(Af + s1 * 8) = a1;
      *(uint4*)(Wf + s0 * 8) = w0;
      *(uint4*)(Wf + s1 * 8) = w1;
    }
    __syncthreads();
    #pragma unroll
    for (int kc = 0; kc < 2; kc++) {
      bf16x8 af[2], wf[2];
      #pragma unroll
      for (int mt = 0; mt < 2; mt++)
        af[mt] = *(const bf16x8*)(Af + (((wm * 2 + mt) * 2 + kc) * 64 + lane) * 8);
      #pragma unroll
      for (int nt = 0; nt < 2; nt++)
        wf[nt] = *(const bf16x8*)(Wf + (((wn * 2 + nt) * 2 + kc) * 64 + lane) * 8);
      #pragma unroll
      for (int mt = 0; mt < 2; mt++)
        #pragma unroll
        for (int nt = 0; nt < 2; nt++)
          acc[mt][nt] = __builtin_amdgcn_mfma_f32_16x16x32_bf16(af[mt], wf[nt], acc[mt][nt], 0, 0, 0);
    }
  }
  #pragma unroll
  for (int nt = 0; nt < 2; nt++) {
    const int col = n0 + (wn * 2 + nt) * 16 + l15;
    const float bv = bias[col];
    #pragma unroll
    for (int mt = 0; mt < 2; mt++) {
      const int rowb = m0 + (wm * 2 + mt) * 16 + q * 4;
      #pragma unroll
      for (int reg = 0; reg < 4; reg++) {
        const int row = rowb + reg;
        float o = acc[mt][nt][reg] + bv;
        if (res) o += res[(size_t)row * N + col];
        if (flags & 1) o = fmaxf(o, 0.f);
        if (flags & 2) ((unsigned short*)Cout)[(size_t)row * N + col] = f2b(o);
        else           ((float*)Cout)[(size_t)row * N + col] = o;
      }
    }
  }
}

// ---------------- 3. masked flash attention, bf16 MFMA ----------------
__global__ __launch_bounds__(256) void attn_mfma(
    const unsigned short* __restrict__ qkv, const unsigned int* __restrict__ bits,
    const float* __restrict__ emb, unsigned short* __restrict__ ctxo) {
  const int bx = blockIdx.x;
  const int ib = bx & 7;
  const int h = (bx >> 3) & 7;
  const int b = bx >> 6;
  const int tid = threadIdx.x;
  const int lane = tid & 63;
  const int wave = tid >> 6;
  const int q = lane >> 4, l15 = lane & 15;

  __shared__ __align__(16) unsigned short kF[4 * 64 * 8];
  __shared__ __align__(16) unsigned short vF[4 * 64 * 8];
  __shared__ __align__(16) unsigned int mrow[64 * 16];
  __shared__ __align__(16) unsigned short pF[4][2 * 64 * 8];

  {
    int rr = tid >> 2, wq = tid & 3;
    uint4 mw = *(const uint4*)(bits + ((size_t)(b * N_ + ib * 64 + rr)) * 16 + wq * 4);
    *(uint4*)(mrow + rr * 16 + wq * 4) = mw;
  }
  const int i0w = ib * 64 + wave * 16;
  const bf16x8 qf = *(const bf16x8*)(qkv + ((size_t)(b * N_ + i0w + l15)) * 768 + h * HD_ + q * 8);
  const float delta = emb[1 * H_ + h] - emb[2 * H_ + h];
  const float scale = 0.17677669529663687f;  // 1/sqrt(32)

  float m_run[4], l_run[4];
  #pragma unroll
  for (int e = 0; e < 4; e++) { m_run[e] = -1e30f; l_run[e] = 0.f; }
  f32x4 cacc[2];
  cacc[0] = (f32x4){0.f, 0.f, 0.f, 0.f};
  cacc[1] = (f32x4){0.f, 0.f, 0.f, 0.f};

  unsigned short* pbase = &pF[wave][0];
  const int sj = tid >> 2, scb = tid & 3;

  #pragma unroll 1
  for (int jt = 0; jt < 8; jt++) {
    __syncthreads();
    {
      const unsigned short* kvrow = qkv + ((size_t)(b * N_ + jt * 64 + sj)) * 768 + h * HD_;
      uint4 kv4 = *(const uint4*)(kvrow + E_ + scb * 8);
      *(uint4*)(kF + (((sj >> 4) * 64) + (sj & 15) + scb * 16) * 8) = kv4;
      uint4 vv4 = *(const uint4*)(kvrow + 2 * E_ + scb * 8);
      const unsigned short* vp = (const unsigned short*)&vv4;
      #pragma unroll
      for (int e2 = 0; e2 < 8; e2++) {
        int d = scb * 8 + e2;
        int slot = ((d >> 4) * 2 + (sj >> 5)) * 64 + (d & 15) + ((sj >> 3) & 3) * 16;
        vF[slot * 8 + (sj & 7)] = vp[e2];
      }
    }
    __syncthreads();
    f32x4 s4[4];
    #pragma unroll
    for (int jtile = 0; jtile < 4; jtile++) {
      bf16x8 kf = *(const bf16x8*)(kF + (jtile * 64 + lane) * 8);
      s4[jtile] = __builtin_amdgcn_mfma_f32_16x16x32_bf16(qf, kf, (f32x4){0.f, 0.f, 0.f, 0.f}, 0, 0, 0);
    }
    unsigned long long mw64[4];
    #pragma unroll
    for (int reg = 0; reg < 4; reg++)
      mw64[reg] = *(const unsigned long long*)(mrow + (wave * 16 + q * 4 + reg) * 16 + jt * 2);
    float smat[4][4];
    #pragma unroll
    for (int jtile = 0; jtile < 4; jtile++) {
      #pragma unroll
      for (int reg = 0; reg < 4; reg++) {
        unsigned int w = (jtile & 2) ? (unsigned int)(mw64[reg] >> 32) : (unsigned int)mw64[reg];
        bool allowed = ((w >> ((jtile & 1) * 16 + l15)) & 1u) != 0u;
        int ig = ib * 64 + wave * 16 + q * 4 + reg;
        int jg = jt * 64 + jtile * 16 + l15;
        float s = s4[jtile][reg] * scale + ((jg == ig) ? delta : 0.f);
        smat[jtile][reg] = allowed ? s : -INFINITY;
      }
    }
    float alpha[4], pmat[4][4];
    #pragma unroll
    for (int reg = 0; reg < 4; reg++) {
      float mloc = fmaxf(fmaxf(smat[0][reg], smat[1][reg]), fmaxf(smat[2][reg], smat[3][reg]));
      #pragma unroll
      for (int off = 1; off < 16; off <<= 1) mloc = fmaxf(mloc, __shfl_xor(mloc, off));
      float mnew = fmaxf(m_run[reg], mloc);
      alpha[reg] = __expf(m_run[reg] - mnew);
      m_run[reg] = mnew;
      float ps = 0.f;
      #pragma unroll
      for (int jtile = 0; jtile < 4; jtile++) {
        float p = __expf(smat[jtile][reg] - mnew);
        pmat[jtile][reg] = p;
        ps += p;
      }
      #pragma unroll
      for (int off = 1; off < 16; off <<= 1) ps += __shfl_xor(ps, off);
      l_run[reg] = l_run[reg] * alpha[reg] + ps;
      cacc[0][reg] *= alpha[reg];
      cacc[1][reg] *= alpha[reg];
    }
    #pragma unroll
    for (int jtile = 0; jtile < 4; jtile++) {
      int j_l = jtile * 16 + l15;
      int sl = ((j_l >> 5) * 64 + ((j_l >> 3) & 3) * 16) * 8 + (j_l & 7);
      #pragma unroll
      for (int reg = 0; reg < 4; reg++)
        pbase[sl + (q * 4 + reg) * 8] = f2b(pmat[jtile][reg]);
    }
    #pragma unroll
    for (int kc = 0; kc < 2; kc++) {
      bf16x8 pf = *(const bf16x8*)(pbase + (kc * 64 + lane) * 8);
      #pragma unroll
      for (int dt = 0; dt < 2; dt++) {
        bf16x8 vf = *(const bf16x8*)(vF + ((dt * 2 + kc) * 64 + lane) * 8);
        cacc[dt] = __builtin_amdgcn_mfma_f32_16x16x32_bf16(pf, vf, cacc[dt], 0, 0, 0);
      }
    }
  }
  #pragma unroll
  for (int reg = 0; reg < 4; reg++) {
    const float linv = 1.f / l_run[reg];
    const size_t row = (size_t)(b * N_ + i0w + q * 4 + reg);
    #pragma unroll
    for (int dt = 0; dt < 2; dt++)
      ctxo[row * E_ + h * HD_ + dt * 16 + l15] = f2b(cacc[dt][reg] * linv);
  }
}

// ---------------- 4. LayerNorm over E=256; optional bf16 out; optional fused
// pooling weight ew[row] = exp(tanh(dot(o, wp) + bp)) ----------------
__global__ __launch_bounds__(256) void layernorm_kernel(
    const float* __restrict__ t, const float* __restrict__ g,
    const float* __restrict__ be, float* __restrict__ out,
    unsigned short* __restrict__ outb, const float* __restrict__ wp,
    const float* __restrict__ bp, float* __restrict__ ew) {
  const int row = blockIdx.x;
  const int tid = threadIdx.x;
  float v = t[(size_t)row * E_ + tid];
  float s = v, s2 = v * v;
  #pragma unroll
  for (int off = 32; off > 0; off >>= 1) {
    s += __shfl_xor(s, off);
    s2 += __shfl_xor(s2, off);
  }
  __shared__ float sh[8];
  const int wave = tid >> 6, lane = tid & 63;
  if (lane == 0) { sh[wave] = s; sh[4 + wave] = s2; }
  __syncthreads();
  s = sh[0] + sh[1] + sh[2] + sh[3];
  s2 = sh[4] + sh[5] + sh[6] + sh[7];
  float mean = s * (1.f / 256.f);
  float var = s2 * (1.f / 256.f) - mean * mean;
  float inv = rsqrtf(var + 1e-5f);
  float o = (v - mean) * inv * g[tid] + be[tid];
  out[(size_t)row * E_ + tid] = o;
  if (outb) outb[(size_t)row * E_ + tid] = f2b(o);
  if (ew) {
    float d = o * wp[tid];
    #pragma unroll
    for (int off = 32; off > 0; off >>= 1) d += __shfl_xor(d, off);
    __syncthreads();
    if (lane == 0) sh[wave] = d;
    __syncthreads();
    if (tid == 0) {
      float dot = sh[0] + sh[1] + sh[2] + sh[3] + bp[0];
      ew[row] = __expf(tanhf(dot));
    }
  }
}

// ---------------- 5a. pooling partial sums: 32 chunks x 8 batches ----------------
__global__ __launch_bounds__(256) void pool_partial(
    const float* __restrict__ x2, const float* __restrict__ ew,
    float* __restrict__ partial, float* __restrict__ pwsum) {
  const int c = blockIdx.x;   // 0..31
  const int b = blockIdx.y;   // 0..7
  const int tid = threadIdx.x;
  const int r0 = b * N_ + c * 16;
  float acc = 0.f;
  #pragma unroll
  for (int n = 0; n < 16; n++)
    acc += ew[r0 + n] * x2[(size_t)(r0 + n) * E_ + tid];
  partial[(size_t)(b * 32 + c) * E_ + tid] = acc;
  if (tid < 16) {
    float w = ew[r0 + tid];
    #pragma unroll
    for (int off = 1; off < 16; off <<= 1) w += __shfl_xor(w, off);
    if (tid == 0) pwsum[b * 32 + c] = w;
  }
}

// ---------------- 5b. pooling final reduce ----------------
__global__ __launch_bounds__(256) void pool_final(
    const float* __restrict__ partial, const float* __restrict__ pwsum,
    float* __restrict__ out) {
  const int b = blockIdx.x;
  const int tid = threadIdx.x;
  float acc = 0.f, ws = 0.f;
  #pragma unroll
  for (int c = 0; c < 32; c++) acc += partial[(size_t)(b * 32 + c) * E_ + tid];
  #pragma unroll
  for (int c = 0; c < 32; c++) ws += pwsum[b * 32 + c];
  out[b * E_ + tid] = acc / ws;
}

// ---------------- launch ----------------
extern "C" void kernel_launch(void* const* d_in, const int* in_sizes, int n_in,
                              void* d_out, int out_size, void* d_ws, size_t ws_size,
                              hipStream_t stream) {
  (void)in_sizes; (void)n_in; (void)out_size; (void)ws_size;
  const float* x      = (const float*)d_in[0];
  const float* adj    = (const float*)d_in[1];
  const float* emb    = (const float*)d_in[2];
  const float* w_qkv  = (const float*)d_in[3];
  const float* b_qkv  = (const float*)d_in[4];
  const float* w_out  = (const float*)d_in[5];
  const float* b_out  = (const float*)d_in[6];
  const float* w_ff1  = (const float*)d_in[7];
  const float* b_ff1  = (const float*)d_in[8];
  const float* w_ff2  = (const float*)d_in[9];
  const float* b_ff2  = (const float*)d_in[10];
  const float* g1     = (const float*)d_in[11];
  const float* be1    = (const float*)d_in[12];
  const float* g2     = (const float*)d_in[13];
  const float* be2    = (const float*)d_in[14];
  const float* w_pool = (const float*)d_in[15];
  const float* b_pool = (const float*)d_in[16];

  char* ws = (char*)d_ws;
  unsigned int*   bits  = (unsigned int*)ws;                       // 256 KB
  unsigned short* xb    = (unsigned short*)(ws + 262144);          // 2 MB
  unsigned short* qkvb  = (unsigned short*)(ws + 2359296);         // 6 MB
  unsigned short* hffb  = xb;                                      // 8 MB reuse
  unsigned short* ctxb  = (unsigned short*)(ws + 8650752);         // 2 MB
  unsigned short* x1b   = (unsigned short*)(ws + 10747904);        // 2 MB
  unsigned short* wqkvb = (unsigned short*)(ws + 12845056);        // 384 KB
  unsigned short* woutb = (unsigned short*)(ws + 13238272);        // 128 KB
  unsigned short* wff1b = (unsigned short*)(ws + 13369344);        // 512 KB
  unsigned short* wff2b = (unsigned short*)(ws + 13893632);        // 512 KB
  float*          tbuf  = (float*)(ws + 14417920);                 // 4 MB
  float*          x1    = (float*)(ws + 18612224);                 // 4 MB
  float*          x2    = (float*)(ws + 22806528);                 // 4 MB
  // pooling scratch reuses ctxb region (dead after out-proj gemm)
  float*          ew      = (float*)(ws + 8650752);                // 16 KB
  float*          partial = (float*)(ws + 8650752 + 16384);        // 256 KB
  float*          pwsum   = (float*)(ws + 8650752 + 16384 + 262144);
  float*          outp  = (float*)d_out;

  const int M = B_ * N_;  // 4096

  cvt_all<<<1835008 / 1024, 256, 0, stream>>>(x, w_qkv, w_out, w_ff1, w_ff2,
                                              xb, wqkvb, woutb, wff1b, wff2b);
  topk_kernel<<<B_ * N_, 256, 0, stream>>>(adj, bits);
  gemm_mfma<<<dim3(768 / 64, M / 64), 256, 0, stream>>>(
      xb, wqkvb, b_qkv, nullptr, qkvb, M, 768, E_, 2);
  attn_mfma<<<B_ * H_ * (N_ / 64), 256, 0, stream>>>(qkvb, bits, emb, ctxb);
  gemm_mfma<<<dim3(E_ / 64, M / 64), 256, 0, stream>>>(
      ctxb, woutb, b_out, x, tbuf, M, E_, E_, 0);
  layernorm_kernel<<<M, 256, 0, stream>>>(tbuf, g1, be1, x1, x1b,
                                          nullptr, nullptr, nullptr);
  gemm_mfma<<<dim3(1024 / 64, M / 64), 256, 0, stream>>>(
      x1b, wff1b, b_ff1, nullptr, hffb, M, 1024, E_, 1 | 2);
  gemm_mfma<<<dim3(E_ / 64, M / 64), 256, 0, stream>>>(
      hffb, wff2b, b_ff2, x1, tbuf, M, E_, 1024, 0);
  layernorm_kernel<<<M, 256, 0, stream>>>(tbuf, g2, be2, x2, nullptr,
                                          w_pool, b_pool, ew);
  pool_partial<<<dim3(32, 8), 256, 0, stream>>>(x2, ew, partial, pwsum);
  pool_final<<<B_, 256, 0, stream>>>(partial, pwsum, outp);
}